// Round 7
// baseline (187.848 us; speedup 1.0000x reference)
//
#include <hip/hip_runtime.h>

// MatrixFactorization: out[i] = dot(user_i, item_table[dest_i])
// user_i = b + sum_k emb_k[idx_k[i]] @ W_k  (W_k = rows [4k,4k+4) of W[24,32])
// Round 7: PAIR-COMBINED projected tables to halve per-row LDS+VALU work:
//   T0 = dow x time (168 entries, bias folded in)   offset 0
//   T1 = sex x month (24)                           offset 168
//   T2 = age (100)                                  offset 192
//   T3 = day (31)                                   offset 292
// 323 entries x 36-float padded stride = 46,512 B LDS -> 3 blocks/CU.
// 512-thread blocks, __launch_bounds__(512,6): 24 waves/CU (75% occ), VGPR
// cap 85. Keep round 6's batched item-row burst + index prefetch + fence.

#define NF 32
#define LDS_STRIDE 36           // floats per padded table row (144 B, 16B-aligned)
#define NV2 323                 // 168 + 24 + 100 + 31 combined entries
#define T1_OFF 168
#define T2_OFF 192
#define T3_OFF 292

__device__ __forceinline__ float4 ldsf4(const float* p) {
    return *reinterpret_cast<const float4*>(p);
}

__device__ __forceinline__ float dot4(float4 u, float4 v, float a) {
    a = fmaf(u.x, v.x, a);
    a = fmaf(u.y, v.y, a);
    a = fmaf(u.z, v.z, a);
    a = fmaf(u.w, v.w, a);
    return a;
}

// one item quad (IV, quad index Q) against 4 combined tables, 4 acc chains
#define QUAD(IV, Q)                                                  \
    acc0 = dot4(ldsf4(&proj[b0 + (Q) * 4]), IV, acc0);               \
    acc1 = dot4(ldsf4(&proj[b1 + (Q) * 4]), IV, acc1);               \
    acc2 = dot4(ldsf4(&proj[b2 + (Q) * 4]), IV, acc2);               \
    acc3 = dot4(ldsf4(&proj[b3 + (Q) * 4]), IV, acc3);

#define NTL(P) __builtin_nontemporal_load(P)

__global__ __launch_bounds__(512, 6)
void mf_kernel(const int* __restrict__ dow, const int* __restrict__ tmi,
               const int* __restrict__ sx,  const int* __restrict__ ag,
               const int* __restrict__ mo,  const int* __restrict__ dy,
               const int* __restrict__ dst,
               const float* __restrict__ e_dow,   const float* __restrict__ e_time,
               const float* __restrict__ e_sex,   const float* __restrict__ e_age,
               const float* __restrict__ e_month, const float* __restrict__ e_day,
               const float* __restrict__ W, const float* __restrict__ bvec,
               const float* __restrict__ item_table,
               float* __restrict__ out, int n)
{
    __shared__ float proj[NV2 * LDS_STRIDE];   // 46,512 B

    // ---- Stage 1: build combined projected tables in LDS ----
    // W row blocks: dow 0-3, time 4-7, sex 8-11, age 12-15, month 16-19, day 20-23
    const int tid = threadIdx.x;
    for (int t = tid; t < NV2 * NF; t += blockDim.x) {
        const int entry = t >> 5;
        const int f     = t & 31;
        float acc;
        if (entry < T1_OFF) {                       // dow x time (+bias)
            const int a = entry / 24;
            const int b = entry - a * 24;
            acc = bvec[f];
            #pragma unroll
            for (int d = 0; d < 4; ++d) {
                acc = fmaf(e_dow[a * 4 + d],  W[(0  + d) * NF + f], acc);
                acc = fmaf(e_time[b * 4 + d], W[(4  + d) * NF + f], acc);
            }
        } else if (entry < T2_OFF) {                // sex x month
            const int e2 = entry - T1_OFF;
            const int a = e2 / 12;
            const int b = e2 - a * 12;
            acc = 0.0f;
            #pragma unroll
            for (int d = 0; d < 4; ++d) {
                acc = fmaf(e_sex[a * 4 + d],   W[(8  + d) * NF + f], acc);
                acc = fmaf(e_month[b * 4 + d], W[(16 + d) * NF + f], acc);
            }
        } else if (entry < T3_OFF) {                // age
            const int v = entry - T2_OFF;
            acc = 0.0f;
            #pragma unroll
            for (int d = 0; d < 4; ++d)
                acc = fmaf(e_age[v * 4 + d], W[(12 + d) * NF + f], acc);
        } else {                                    // day
            const int v = entry - T3_OFF;
            acc = 0.0f;
            #pragma unroll
            for (int d = 0; d < 4; ++d)
                acc = fmaf(e_day[v * 4 + d], W[(20 + d) * NF + f], acc);
        }
        proj[entry * LDS_STRIDE + f] = acc;
    }
    __syncthreads();

    // ---- Stage 2: 1 row/thread, grid-stride, 2-deep index pipeline ----
    const int tstride = gridDim.x * blockDim.x;
    int i = blockIdx.x * blockDim.x + tid;
    if (i >= n) return;

    int j0 = NTL(&dow[i]), j1 = NTL(&tmi[i]), j2 = NTL(&sx[i]),
        j3 = NTL(&ag[i]),  j4 = NTL(&mo[i]),  j5 = NTL(&dy[i]),
        jd = NTL(&dst[i]);

    for (;;) {
        const int b0 = (j0 * 24 + j1) * LDS_STRIDE;            // dow x time
        const int b1 = (T1_OFF + j2 * 12 + j4) * LDS_STRIDE;   // sex x month
        const int b2 = (T2_OFF + j3) * LDS_STRIDE;             // age
        const int b3 = (T3_OFF + j5) * LDS_STRIDE;             // day
        const float4* it = reinterpret_cast<const float4*>(item_table + (long long)jd * NF);

        // whole 128 B item row (one L2 line) in one burst
        float4 iv0 = it[0];
        float4 iv1 = it[1];
        float4 iv2 = it[2];
        float4 iv3 = it[3];
        float4 iv4 = it[4];
        float4 iv5 = it[5];
        float4 iv6 = it[6];
        float4 iv7 = it[7];

        // prefetch next trip's indices while the item row is in flight
        const int ni = i + tstride;
        const bool more = ni < n;          // wave-uniform (n multiple of 64)
        if (more) {
            j0 = NTL(&dow[ni]); j1 = NTL(&tmi[ni]); j2 = NTL(&sx[ni]);
            j3 = NTL(&ag[ni]);  j4 = NTL(&mo[ni]);  j5 = NTL(&dy[ni]);
            jd = NTL(&dst[ni]);
        }

        // fence: no load may be sunk below this point -> one batched vmcnt wait
        asm volatile("" ::: "memory");

        float acc0 = 0.0f, acc1 = 0.0f, acc2 = 0.0f, acc3 = 0.0f;
        QUAD(iv0, 0)
        QUAD(iv1, 1)
        QUAD(iv2, 2)
        QUAD(iv3, 3)
        QUAD(iv4, 4)
        QUAD(iv5, 5)
        QUAD(iv6, 6)
        QUAD(iv7, 7)
        __builtin_nontemporal_store((acc0 + acc1) + (acc2 + acc3), &out[i]);

        if (!more) break;
        i = ni;
    }
}

extern "C" void kernel_launch(void* const* d_in, const int* in_sizes, int n_in,
                              void* d_out, int out_size, void* d_ws, size_t ws_size,
                              hipStream_t stream) {
    const int* dow = (const int*)d_in[0];
    const int* tmi = (const int*)d_in[1];
    const int* sx  = (const int*)d_in[2];
    const int* ag  = (const int*)d_in[3];
    const int* mo  = (const int*)d_in[4];
    const int* dy  = (const int*)d_in[5];
    const int* dst = (const int*)d_in[6];
    const float* e_dow   = (const float*)d_in[7];
    const float* e_time  = (const float*)d_in[8];
    const float* e_sex   = (const float*)d_in[9];
    const float* e_age   = (const float*)d_in[10];
    const float* e_month = (const float*)d_in[11];
    const float* e_day   = (const float*)d_in[12];
    const float* W       = (const float*)d_in[13];
    const float* bvec    = (const float*)d_in[14];
    const float* item    = (const float*)d_in[15];
    float* out = (float*)d_out;
    const int n = in_sizes[0];

    // 512 threads x 1024 blocks = 524,288 threads -> exactly 4 trips at N=2M
    dim3 grid(1024), block(512);
    mf_kernel<<<grid, block, 0, stream>>>(dow, tmi, sx, ag, mo, dy, dst,
                                          e_dow, e_time, e_sex, e_age, e_month, e_day,
                                          W, bvec, item, out, n);
}

// Round 8
// 170.802 us; speedup vs baseline: 1.0998x; 1.0998x over previous
//
#include <hip/hip_runtime.h>

// MatrixFactorization: out[i] = dot(user_i, item_table[dest_i])
// user_i = b + sum_k emb_k[idx_k[i]] @ W_k  (W_k = rows [4k,4k+4) of W[24,32])
// Round 8: round 6 structure (single per-feature projected tables: keeps the
// LDS broadcast for small vocabs — round 7's pair-combined tables tripled
// bank conflicts and regressed) with occupancy raised: __launch_bounds__(256,6)
// -> 6 blocks/CU (LDS-capped: 6 x 25.6 KB = 153.6 KB), grid 1536 = exactly
// resident, 24 waves/CU. Burst item-row load + index prefetch + fence kept.

#define NF 32
#define LDS_STRIDE 36           // floats per padded table row (144 B, 16B-aligned)
#define NV 176                  // 7+24+2+100+12+31 vocab entries

__device__ __forceinline__ float4 ldsf4(const float* p) {
    return *reinterpret_cast<const float4*>(p);
}

__device__ __forceinline__ float dot4(float4 u, float4 v, float a) {
    a = fmaf(u.x, v.x, a);
    a = fmaf(u.y, v.y, a);
    a = fmaf(u.z, v.z, a);
    a = fmaf(u.w, v.w, a);
    return a;
}

// one item quad (IV, quad index Q) against all 6 user tables, 3 acc chains
#define QUAD(IV, Q)                                                  \
    acc0 = dot4(ldsf4(&proj[b0 + (Q) * 4]), IV, acc0);               \
    acc1 = dot4(ldsf4(&proj[b1 + (Q) * 4]), IV, acc1);               \
    acc2 = dot4(ldsf4(&proj[b2 + (Q) * 4]), IV, acc2);               \
    acc0 = dot4(ldsf4(&proj[b3 + (Q) * 4]), IV, acc0);               \
    acc1 = dot4(ldsf4(&proj[b4 + (Q) * 4]), IV, acc1);               \
    acc2 = dot4(ldsf4(&proj[b5 + (Q) * 4]), IV, acc2);

#define NTL(P) __builtin_nontemporal_load(P)

__global__ __launch_bounds__(256, 6)
void mf_kernel(const int* __restrict__ dow, const int* __restrict__ tmi,
               const int* __restrict__ sx,  const int* __restrict__ ag,
               const int* __restrict__ mo,  const int* __restrict__ dy,
               const int* __restrict__ dst,
               const float* __restrict__ e_dow,   const float* __restrict__ e_time,
               const float* __restrict__ e_sex,   const float* __restrict__ e_age,
               const float* __restrict__ e_month, const float* __restrict__ e_day,
               const float* __restrict__ W, const float* __restrict__ bvec,
               const float* __restrict__ item_table,
               float* __restrict__ out, int n)
{
    __shared__ float proj[NV * LDS_STRIDE];   // 25,344 B

    // ---- Stage 1: build projected vocab tables in LDS ----
    // entry ranges: dow [0,7) time [7,31) sex [31,33) age [33,133) month [133,145) day [145,176)
    const int tid = threadIdx.x;
    for (int t = tid; t < NV * NF; t += blockDim.x) {
        int entry = t >> 5;
        int f     = t & 31;
        int k, v;
        const float* e;
        if      (entry < 7)   { k = 0; v = entry;       e = e_dow;   }
        else if (entry < 31)  { k = 1; v = entry - 7;   e = e_time;  }
        else if (entry < 33)  { k = 2; v = entry - 31;  e = e_sex;   }
        else if (entry < 133) { k = 3; v = entry - 33;  e = e_age;   }
        else if (entry < 145) { k = 4; v = entry - 133; e = e_month; }
        else                  { k = 5; v = entry - 145; e = e_day;   }
        float acc = (k == 0) ? bvec[f] : 0.0f;
        #pragma unroll
        for (int d = 0; d < 4; ++d)
            acc += e[v * 4 + d] * W[(k * 4 + d) * NF + f];
        proj[entry * LDS_STRIDE + f] = acc;
    }
    __syncthreads();

    // ---- Stage 2: 1 row/thread, grid-stride, 2-deep index pipeline ----
    const int tstride = gridDim.x * blockDim.x;
    int i = blockIdx.x * blockDim.x + tid;
    if (i >= n) return;

    // prologue: indices for first trip
    int j0 = NTL(&dow[i]), j1 = NTL(&tmi[i]), j2 = NTL(&sx[i]),
        j3 = NTL(&ag[i]),  j4 = NTL(&mo[i]),  j5 = NTL(&dy[i]),
        jd = NTL(&dst[i]);

    for (;;) {
        const int b0 = (0   + j0) * LDS_STRIDE;
        const int b1 = (7   + j1) * LDS_STRIDE;
        const int b2 = (31  + j2) * LDS_STRIDE;
        const int b3 = (33  + j3) * LDS_STRIDE;
        const int b4 = (133 + j4) * LDS_STRIDE;
        const int b5 = (145 + j5) * LDS_STRIDE;
        const float4* it = reinterpret_cast<const float4*>(item_table + (long long)jd * NF);

        // whole 128 B item row (one L2 line) in one burst
        float4 iv0 = it[0];
        float4 iv1 = it[1];
        float4 iv2 = it[2];
        float4 iv3 = it[3];
        float4 iv4 = it[4];
        float4 iv5 = it[5];
        float4 iv6 = it[6];
        float4 iv7 = it[7];

        // prefetch next trip's indices while the item row is in flight
        const int ni = i + tstride;
        const bool more = ni < n;          // wave-uniform (n, stride multiples of 64)
        if (more) {
            j0 = NTL(&dow[ni]); j1 = NTL(&tmi[ni]); j2 = NTL(&sx[ni]);
            j3 = NTL(&ag[ni]);  j4 = NTL(&mo[ni]);  j5 = NTL(&dy[ni]);
            jd = NTL(&dst[ni]);
        }

        // fence: no load may be sunk below this point -> one batched vmcnt wait
        asm volatile("" ::: "memory");

        float acc0 = 0.0f, acc1 = 0.0f, acc2 = 0.0f;
        QUAD(iv0, 0)
        QUAD(iv1, 1)
        QUAD(iv2, 2)
        QUAD(iv3, 3)
        QUAD(iv4, 4)
        QUAD(iv5, 5)
        QUAD(iv6, 6)
        QUAD(iv7, 7)
        __builtin_nontemporal_store(acc0 + acc1 + acc2, &out[i]);

        if (!more) break;
        i = ni;
    }
}

extern "C" void kernel_launch(void* const* d_in, const int* in_sizes, int n_in,
                              void* d_out, int out_size, void* d_ws, size_t ws_size,
                              hipStream_t stream) {
    const int* dow = (const int*)d_in[0];
    const int* tmi = (const int*)d_in[1];
    const int* sx  = (const int*)d_in[2];
    const int* ag  = (const int*)d_in[3];
    const int* mo  = (const int*)d_in[4];
    const int* dy  = (const int*)d_in[5];
    const int* dst = (const int*)d_in[6];
    const float* e_dow   = (const float*)d_in[7];
    const float* e_time  = (const float*)d_in[8];
    const float* e_sex   = (const float*)d_in[9];
    const float* e_age   = (const float*)d_in[10];
    const float* e_month = (const float*)d_in[11];
    const float* e_day   = (const float*)d_in[12];
    const float* W       = (const float*)d_in[13];
    const float* bvec    = (const float*)d_in[14];
    const float* item    = (const float*)d_in[15];
    float* out = (float*)d_out;
    const int n = in_sizes[0];

    // 1536 blocks = 6/CU resident (LDS-capped), multiple of 8 XCDs;
    // grid-stride ~5.3 trips/thread at N=2M.
    dim3 grid(1536), block(256);
    mf_kernel<<<grid, block, 0, stream>>>(dow, tmi, sx, ag, mo, dy, dst,
                                          e_dow, e_time, e_sex, e_age, e_month, e_day,
                                          W, bvec, item, out, n);
}